// Round 4
// baseline (442.311 us; speedup 1.0000x reference)
//
#include <hip/hip_runtime.h>
#include <hip/hip_bf16.h>
#include <math.h>

#define NN    8192
#define FIN   256
#define HID   64
#define NH    4
#define NC    16
#define MAXD  128
#define ALPHA 0.2f
#define GRID  1024
#define KC    32
#define GEMM_BLOCKS 512
#define SPIN_BOUND  400000

struct AttnShared {
    int   colsS[MAXD];
    int   cnt;
    int   gflag;
    int   colsA[MAXD];
    float2 pc[NH][MAXD];       // packed (coef, bitcast(col)) per head
    float h1[NH*HID];
    float red[16][17];
    float f2s[NC];
};

union MegaShared {
    struct { float xsT[KC][68]; float w[KC][68]; } g;    // gemm stage (17.4KB)
    struct { float r1[64][17];  float r2[64][17]; } gr;  // gemm epilogue
    AttnShared a;
};

// One row of layer-1 attention + h1 concat + fts2 projection + g1/g2 scalars.
__device__ __forceinline__ void attn_row(
    AttnShared& sa, int r, int t, int h, int lane,
    const int* __restrict__ deg, const int* __restrict__ cols,
    const float* __restrict__ fts1, const float* __restrict__ f1v,
    const float* __restrict__ f2v, const float* __restrict__ bias1,
    const float* __restrict__ W2, const float* __restrict__ a2s,
    const float* __restrict__ a2d, const float* __restrict__ b2s,
    const float* __restrict__ b2d,
    float* __restrict__ fts2, float* __restrict__ g1, float* __restrict__ g2)
{
    __syncthreads();                               // colsA/pc/h1 reuse guard
    const int d = deg[r];
    if (t < MAXD) sa.colsA[t] = cols[(size_t)r*MAXD + t];
    __syncthreads();

    const float f1i = f1v[r*NH + h];
    const int c0 = sa.colsA[lane], c1 = sa.colsA[lane + 64];
    float sc0 = -1e30f, sc1 = -1e30f;
    if (lane < d)      { const float x = f1i + f2v[c0*NH + h]; sc0 = x > 0.f ? x : ALPHA*x; }
    if (lane + 64 < d) { const float x = f1i + f2v[c1*NH + h]; sc1 = x > 0.f ? x : ALPHA*x; }
    float m = fmaxf(sc0, sc1);
    #pragma unroll
    for (int off = 32; off; off >>= 1) m = fmaxf(m, __shfl_xor(m, off));
    const float p0 = (lane      < d) ? expf(sc0 - m) : 0.f;
    const float p1 = (lane + 64 < d) ? expf(sc1 - m) : 0.f;
    sa.pc[h][lane]      = make_float2(p0, __int_as_float(c0));
    sa.pc[h][lane + 64] = make_float2(p1, __int_as_float(c1));
    float sum = p0 + p1;
    #pragma unroll
    for (int off = 32; off; off >>= 1) sum += __shfl_xor(sum, off);
    const float inv = 1.f / sum;

    // PV: pc[h][*] written and read by the same wave; e uniform -> LDS broadcast
    float acc = 0.f;
    #pragma unroll 8
    for (int e = 0; e < d; ++e) {
        const float2 q = sa.pc[h][e];
        acc += q.x * fts1[((size_t)__float_as_int(q.y)*NH + h)*HID + lane];
    }
    const float v = acc*inv + bias1[h*HID + lane];
    sa.h1[h*HID + lane] = v > 0.f ? v : expm1f(v);   // elu, concat layout
    __syncthreads();

    {   // fts2 = h1 @ W2  ([256] x [256,16])
        const int c = t & 15, part = t >> 4;
        float s = 0.f;
        #pragma unroll
        for (int q2 = 0; q2 < 16; ++q2) s += sa.h1[part*16 + q2] * W2[(part*16 + q2)*NC + c];
        sa.red[part][c] = s;
    }
    __syncthreads();
    if (t < NC) {
        float s = 0.f;
        #pragma unroll
        for (int q2 = 0; q2 < 16; ++q2) s += sa.red[q2][t];
        sa.f2s[t] = s;
        fts2[(size_t)r*NC + t] = s;
    }
    __syncthreads();
    if (t == 0) {
        float s1 = b2s[0], s2 = b2d[0];
        #pragma unroll
        for (int c = 0; c < NC; ++c) { s1 += sa.f2s[c]*a2s[c]; s2 += sa.f2s[c]*a2d[c]; }
        g1[r] = s1; g2[r] = s2;
    }
}

// Mega-kernel: blocks 0..511 do one gemm tile then release ctr; all 1024 blocks
// run a register-pipelined {scan -> CSR -> inline attn1} loop over their rows.
__global__ __launch_bounds__(256, 4) void k_mega(
    const float* __restrict__ bias, const float* __restrict__ seq,
    const float* __restrict__ W1, const float* __restrict__ a1s,
    const float* __restrict__ a1d, const float* __restrict__ b1s,
    const float* __restrict__ b1d, const float* __restrict__ bias1,
    const float* __restrict__ W2, const float* __restrict__ a2s,
    const float* __restrict__ a2d, const float* __restrict__ b2s,
    const float* __restrict__ b2d,
    int* __restrict__ ctr, int* __restrict__ deg, int* __restrict__ cols,
    float* __restrict__ fts1, float* __restrict__ f1v, float* __restrict__ f2v,
    float* __restrict__ fts2, float* __restrict__ g1, float* __restrict__ g2)
{
    __shared__ MegaShared S;
    const int t = threadIdx.x, b = blockIdx.x;
    const int h = t >> 6, lane = t & 63;

    if (b < GEMM_BLOCKS) {
        // ---- fts1 tile: 64 nodes x 64 hid, one head; xsT transposed for b128 reads
        const int head = b & 3, rowbase = (b >> 2) * 64;
        const int tr = t >> 4, tc = t & 15;
        float acc[4][4] = {};
        for (int kc = 0; kc < FIN / KC; ++kc) {
            #pragma unroll
            for (int i = 0; i < 2; ++i) {
                const int lin = t + i*256;
                const int row = lin >> 3, kq = lin & 7;
                const float4 v = *(const float4*)(seq + (size_t)(rowbase + row)*FIN + kc*KC + kq*4);
                S.g.xsT[kq*4+0][row] = v.x;
                S.g.xsT[kq*4+1][row] = v.y;
                S.g.xsT[kq*4+2][row] = v.z;
                S.g.xsT[kq*4+3][row] = v.w;
            }
            #pragma unroll
            for (int i = 0; i < 2; ++i) {
                const int lin = t + i*256;
                const int k = lin >> 4, dq = lin & 15;
                *(float4*)&S.g.w[k][dq*4] =
                    *(const float4*)(W1 + ((size_t)head*FIN + kc*KC + k)*HID + dq*4);
            }
            __syncthreads();
            #pragma unroll 8
            for (int k = 0; k < KC; ++k) {
                const float4 aa = *(const float4*)&S.g.xsT[k][tr*4];
                const float4 bb = *(const float4*)&S.g.w[k][tc*4];
                acc[0][0] += aa.x*bb.x; acc[0][1] += aa.x*bb.y; acc[0][2] += aa.x*bb.z; acc[0][3] += aa.x*bb.w;
                acc[1][0] += aa.y*bb.x; acc[1][1] += aa.y*bb.y; acc[1][2] += aa.y*bb.z; acc[1][3] += aa.y*bb.w;
                acc[2][0] += aa.z*bb.x; acc[2][1] += aa.z*bb.y; acc[2][2] += aa.z*bb.z; acc[2][3] += aa.z*bb.w;
                acc[3][0] += aa.w*bb.x; acc[3][1] += aa.w*bb.y; acc[3][2] += aa.w*bb.z; acc[3][3] += aa.w*bb.w;
            }
            __syncthreads();
        }
        float p1[4], p2[4];
        #pragma unroll
        for (int i = 0; i < 4; ++i) {
            const int node = rowbase + tr*4 + i;
            float4 o; o.x = acc[i][0]; o.y = acc[i][1]; o.z = acc[i][2]; o.w = acc[i][3];
            *(float4*)&fts1[((size_t)node*NH + head)*HID + tc*4] = o;
            float s1 = 0.f, s2 = 0.f;
            #pragma unroll
            for (int j = 0; j < 4; ++j) {
                s1 += acc[i][j] * a1s[head*HID + tc*4 + j];
                s2 += acc[i][j] * a1d[head*HID + tc*4 + j];
            }
            p1[i] = s1; p2[i] = s2;
        }
        #pragma unroll
        for (int i = 0; i < 4; ++i) {
            S.gr.r1[tr*4 + i][tc] = p1[i];
            S.gr.r2[tr*4 + i][tc] = p2[i];
        }
        __syncthreads();
        if (t < 64) {
            float s1 = b1s[head], s2 = b1d[head];
            #pragma unroll
            for (int q = 0; q < 16; ++q) { s1 += S.gr.r1[t][q]; s2 += S.gr.r2[t][q]; }
            f1v[(rowbase + t)*NH + head] = s1;
            f2v[(rowbase + t)*NH + head] = s2;
        }
        __syncthreads();
        __threadfence();
        if (t == 0) atomicAdd(ctr, 1);     // release
    }

    // ---- pipelined scan + inline attn over this block's rows ----
    const int R    = (b < GEMM_BLOCKS) ? 6 : 10;
    const int base = (b < GEMM_BLOCKS) ? (5120 + b*6) : ((b - 512)*10);
    bool gemmSeen = false;
    int  a_idx = 0;

    float4 vv[8];
    {
        const float4* rp = (const float4*)(bias + (size_t)base * NN);
        #pragma unroll
        for (int k = 0; k < 8; ++k) vv[k] = rp[k*256 + t];
    }

    for (int j = 0; j < R; ++j) {
        const int row = base + j;
        __syncthreads();
        if (t == 0) S.a.cnt = 0;
        __syncthreads();
        #pragma unroll
        for (int k = 0; k < 8; ++k) {
            const float4 v = vv[k];
            const int cb = (k*256 + t) * 4;
            if (v.x == 0.f) { int p = atomicAdd(&S.a.cnt, 1); if (p < MAXD) S.a.colsS[p] = cb;     }
            if (v.y == 0.f) { int p = atomicAdd(&S.a.cnt, 1); if (p < MAXD) S.a.colsS[p] = cb + 1; }
            if (v.z == 0.f) { int p = atomicAdd(&S.a.cnt, 1); if (p < MAXD) S.a.colsS[p] = cb + 2; }
            if (v.w == 0.f) { int p = atomicAdd(&S.a.cnt, 1); if (p < MAXD) S.a.colsS[p] = cb + 3; }
        }
        if (j + 1 < R) {   // keep HBM stream busy through the attn phase
            const float4* rn = (const float4*)(bias + (size_t)(row + 1) * NN);
            #pragma unroll
            for (int k = 0; k < 8; ++k) vv[k] = rn[k*256 + t];
        }
        if (!gemmSeen && t < 64) {                 // non-blocking poll, 1 coalesced RMW
            const int v = atomicAdd(ctr, 0);
            if (t == 0) S.a.gflag = (v >= GEMM_BLOCKS);
        }
        __syncthreads();
        {   // persist CSR
            if (t < MAXD) cols[(size_t)row*MAXD + t] = S.a.colsS[t];
            if (t == 0)   deg[row] = S.a.cnt < MAXD ? S.a.cnt : MAXD;
        }
        if (!gemmSeen && S.a.gflag) { gemmSeen = true; __threadfence(); }
        int budget = 2;
        while (gemmSeen && a_idx <= j && budget > 0) {
            attn_row(S.a, base + a_idx, t, h, lane, deg, cols, fts1, f1v, f2v,
                     bias1, W2, a2s, a2d, b2s, b2d, fts2, g1, g2);
            ++a_idx; --budget;
        }
    }

    if (a_idx < R) {
        if (!gemmSeen) {                            // rare: bounded sleep-spin
            if (t < 64) {
                for (int it = 0; it < SPIN_BOUND; ++it) {
                    if (atomicAdd(ctr, 0) >= GEMM_BLOCKS) break;
                    __builtin_amdgcn_s_sleep(2);
                }
            }
            __syncthreads();
            __threadfence();
            gemmSeen = true;
        }
        while (a_idx < R) {
            attn_row(S.a, base + a_idx, t, h, lane, deg, cols, fts1, f1v, f2v,
                     bias1, W2, a2s, a2d, b2s, b2d, fts2, g1, g2);
            ++a_idx;
        }
    }
}

// ---------------------------------------------------------------------------
// Layer-2 sparse attention, 1 wave/node, 4 nodes/block (unchanged from R2).
// ---------------------------------------------------------------------------
__global__ __launch_bounds__(256) void k_attn2(
    const float* __restrict__ fts2, const float* __restrict__ g1,
    const float* __restrict__ g2, const float* __restrict__ bias2,
    const int* __restrict__ deg, const int* __restrict__ cols,
    float* __restrict__ out)
{
    __shared__ int   colsS[4][MAXD];
    __shared__ float coefS[4][MAXD];
    const int t = threadIdx.x, w = t >> 6, lane = t & 63;
    const int i = blockIdx.x*4 + w;
    const int d = deg[i];
    for (int e = lane; e < MAXD; e += 64) colsS[w][e] = (e < d) ? cols[(size_t)i*MAXD + e] : 0;

    const float g1i = g1[i];
    float sc0 = -1e30f, sc1 = -1e30f;
    if (lane < d)      { const float x = g1i + g2[colsS[w][lane]];    sc0 = x > 0.f ? x : ALPHA*x; }
    if (lane + 64 < d) { const float x = g1i + g2[colsS[w][lane+64]]; sc1 = x > 0.f ? x : ALPHA*x; }
    float m = fmaxf(sc0, sc1);
    #pragma unroll
    for (int off = 32; off; off >>= 1) m = fmaxf(m, __shfl_xor(m, off));
    const float p0 = (lane      < d) ? expf(sc0 - m) : 0.f;
    const float p1 = (lane + 64 < d) ? expf(sc1 - m) : 0.f;
    coefS[w][lane] = p0; coefS[w][lane + 64] = p1;
    float sum = p0 + p1;
    #pragma unroll
    for (int off = 32; off; off >>= 1) sum += __shfl_xor(sum, off);
    const float inv = 1.f / sum;

    const int eg = lane >> 4, c = lane & 15;
    float acc = 0.f;
    #pragma unroll 2
    for (int e0 = 0; e0 < d; e0 += 4) {
        const int e = e0 + eg;
        if (e < d) acc += coefS[w][e] * fts2[(size_t)colsS[w][e]*NC + c];
    }
    acc += __shfl_xor(acc, 16);
    acc += __shfl_xor(acc, 32);
    if (lane < NC) out[(size_t)i*NC + lane] = acc*inv + bias2[lane];
}

// ---------------------------------------------------------------------------
extern "C" void kernel_launch(void* const* d_in, const int* in_sizes, int n_in,
                              void* d_out, int out_size, void* d_ws, size_t ws_size,
                              hipStream_t stream)
{
    const float* seq   = (const float*)d_in[0];
    const float* bias  = (const float*)d_in[1];
    const float* W1    = (const float*)d_in[2];
    const float* a1s   = (const float*)d_in[3];
    const float* a1d   = (const float*)d_in[4];
    const float* b1s   = (const float*)d_in[5];
    const float* b1d   = (const float*)d_in[6];
    const float* bias1 = (const float*)d_in[7];
    const float* W2    = (const float*)d_in[8];
    const float* a2s   = (const float*)d_in[9];
    const float* a2d   = (const float*)d_in[10];
    const float* b2s   = (const float*)d_in[11];
    const float* b2d   = (const float*)d_in[12];
    const float* bias2 = (const float*)d_in[13];

    char* ws = (char*)d_ws;
    int*   ctr  = (int*)ws;    ws += 256;
    int*   deg  = (int*)ws;    ws += (size_t)NN * 4;
    int*   cols = (int*)ws;    ws += (size_t)NN * MAXD * 4;
    float* fts1 = (float*)ws;  ws += (size_t)NN * NH * HID * 4;
    float* f1v  = (float*)ws;  ws += (size_t)NN * NH * 4;
    float* f2v  = (float*)ws;  ws += (size_t)NN * NH * 4;
    float* fts2 = (float*)ws;  ws += (size_t)NN * NC * 4;
    float* g1   = (float*)ws;  ws += (size_t)NN * 4;
    float* g2   = (float*)ws;  ws += (size_t)NN * 4;

    hipMemsetAsync(ctr, 0, 64, stream);   // reset release counter every launch
    hipLaunchKernelGGL(k_mega, dim3(GRID), dim3(256), 0, stream,
                       bias, seq, W1, a1s, a1d, b1s, b1d, bias1, W2, a2s, a2d,
                       b2s, b2d, ctr, deg, cols, fts1, f1v, f2v, fts2, g1, g2);
    hipLaunchKernelGGL(k_attn2, dim3(NN/4), dim3(256), 0, stream,
                       fts2, g1, g2, bias2, deg, cols, (float*)d_out);
}

// Round 5
// 116.121 us; speedup vs baseline: 3.8090x; 3.8090x over previous
//
#include <hip/hip_runtime.h>
#include <hip/hip_bf16.h>
#include <math.h>

#define NN    8192
#define FIN   256
#define HID   64
#define NH    4
#define NC    16
#define MAXD  128
#define ALPHA 0.2f
#define KC    32

// ---------------------------------------------------------------------------
// K1: fts1 = x @ W1 per head + f1/f2 scalars (packed [node][head] = float4).
// 512 blocks = 128 row-tiles x 4 heads. xsT transposed so both LDS operand
// reads are b128. Proven in R4 (ran inside mega, absmax 1.2e-4).
// ---------------------------------------------------------------------------
__global__ __launch_bounds__(256) void k_gemm(
    const float* __restrict__ seq, const float* __restrict__ W1,
    const float* __restrict__ a1s, const float* __restrict__ a1d,
    const float* __restrict__ b1s, const float* __restrict__ b1d,
    float* __restrict__ fts1, float* __restrict__ f1v, float* __restrict__ f2v)
{
    __shared__ union {
        struct { float xsT[KC][68]; float w[KC][68]; } g;
        struct { float r1[64][17];  float r2[64][17]; } gr;
    } S;
    const int t = threadIdx.x, b = blockIdx.x;
    const int head = b & 3, rowbase = (b >> 2) * 64;
    const int tr = t >> 4, tc = t & 15;

    float acc[4][4] = {};
    for (int kc = 0; kc < FIN / KC; ++kc) {
        #pragma unroll
        for (int i = 0; i < 2; ++i) {
            const int lin = t + i*256;
            const int row = lin >> 3, kq = lin & 7;
            const float4 v = *(const float4*)(seq + (size_t)(rowbase + row)*FIN + kc*KC + kq*4);
            S.g.xsT[kq*4+0][row] = v.x;
            S.g.xsT[kq*4+1][row] = v.y;
            S.g.xsT[kq*4+2][row] = v.z;
            S.g.xsT[kq*4+3][row] = v.w;
        }
        #pragma unroll
        for (int i = 0; i < 2; ++i) {
            const int lin = t + i*256;
            const int k = lin >> 4, dq = lin & 15;
            *(float4*)&S.g.w[k][dq*4] =
                *(const float4*)(W1 + ((size_t)head*FIN + kc*KC + k)*HID + dq*4);
        }
        __syncthreads();
        #pragma unroll 8
        for (int k = 0; k < KC; ++k) {
            const float4 aa = *(const float4*)&S.g.xsT[k][tr*4];
            const float4 bb = *(const float4*)&S.g.w[k][tc*4];
            acc[0][0] += aa.x*bb.x; acc[0][1] += aa.x*bb.y; acc[0][2] += aa.x*bb.z; acc[0][3] += aa.x*bb.w;
            acc[1][0] += aa.y*bb.x; acc[1][1] += aa.y*bb.y; acc[1][2] += aa.y*bb.z; acc[1][3] += aa.y*bb.w;
            acc[2][0] += aa.z*bb.x; acc[2][1] += aa.z*bb.y; acc[2][2] += aa.z*bb.z; acc[2][3] += aa.z*bb.w;
            acc[3][0] += aa.w*bb.x; acc[3][1] += aa.w*bb.y; acc[3][2] += aa.w*bb.z; acc[3][3] += aa.w*bb.w;
        }
        __syncthreads();
    }
    float p1[4], p2[4];
    #pragma unroll
    for (int i = 0; i < 4; ++i) {
        const int node = rowbase + tr*4 + i;
        float4 o; o.x = acc[i][0]; o.y = acc[i][1]; o.z = acc[i][2]; o.w = acc[i][3];
        *(float4*)&fts1[((size_t)node*NH + head)*HID + tc*4] = o;
        float s1 = 0.f, s2 = 0.f;
        #pragma unroll
        for (int j = 0; j < 4; ++j) {
            s1 += acc[i][j] * a1s[head*HID + tc*4 + j];
            s2 += acc[i][j] * a1d[head*HID + tc*4 + j];
        }
        p1[i] = s1; p2[i] = s2;
    }
    #pragma unroll
    for (int i = 0; i < 4; ++i) {
        S.gr.r1[tr*4 + i][tc] = p1[i];
        S.gr.r2[tr*4 + i][tc] = p2[i];
    }
    __syncthreads();
    if (t < 64) {
        float s1 = b1s[head], s2 = b1d[head];
        #pragma unroll
        for (int q = 0; q < 16; ++q) { s1 += S.gr.r1[t][q]; s2 += S.gr.r2[t][q]; }
        f1v[(rowbase + t)*NH + head] = s1;   // [node][head] -> float4-packable
        f2v[(rowbase + t)*NH + head] = s2;
    }
}

// ---------------------------------------------------------------------------
// K2: barrier-free fused {scan -> CSR} + {layer-1 attn, all 4 heads in one
// wave} + {elu/concat, fts2 = h1@W2, g1/g2}. ONE WAVE PER ROW, 4 rows/block,
// zero __syncthreads: scan-streaming waves and attn waves co-schedule.
// ---------------------------------------------------------------------------
__global__ __launch_bounds__(256) void k_scan_attn(
    const float* __restrict__ bias, const float* __restrict__ fts1,
    const float* __restrict__ f1v4, const float* __restrict__ f2v4,
    const float* __restrict__ bias1, const float* __restrict__ W2,
    const float* __restrict__ a2s, const float* __restrict__ a2d,
    const float* __restrict__ b2s, const float* __restrict__ b2d,
    int* __restrict__ deg, int* __restrict__ cols,
    float* __restrict__ fts2, float* __restrict__ g1, float* __restrict__ g2)
{
    __shared__ int    colsS[4][MAXD];
    __shared__ float4 coefS[4][MAXD];
    __shared__ float  h1S[4][NH*HID];

    const int t = threadIdx.x, w = t >> 6, lane = t & 63;
    const int row = blockIdx.x*4 + w;
    const unsigned long long lt = (1ull << lane) - 1ull;

    colsS[w][lane] = 0; colsS[w][64 + lane] = 0;

    // ---- scan: 32KB row, 32 float4/lane in 4 super-iters, chunk-granular
    //      software pipeline (reload vv[k] for s+1 right after consuming) ----
    const float4* rp = (const float4*)(bias + (size_t)row * NN);
    float4 vv[8];
    #pragma unroll
    for (int k = 0; k < 8; ++k) vv[k] = rp[k*64 + lane];
    int base = 0;
    #pragma unroll
    for (int s = 0; s < 4; ++s) {
        #pragma unroll
        for (int k = 0; k < 8; ++k) {
            const float4 v = vv[k];
            if (s < 3) vv[k] = rp[((s+1)*8 + k)*64 + lane];
            const unsigned long long m0 = __ballot(v.x == 0.f);
            const unsigned long long m1 = __ballot(v.y == 0.f);
            const unsigned long long m2 = __ballot(v.z == 0.f);
            const unsigned long long m3 = __ballot(v.w == 0.f);
            const int cb = ((s*8 + k)*64 + lane)*4;
            int p = base + __popcll(m0&lt) + __popcll(m1&lt)
                         + __popcll(m2&lt) + __popcll(m3&lt);
            if (v.x == 0.f) { if (p < MAXD) colsS[w][p] = cb;     ++p; }
            if (v.y == 0.f) { if (p < MAXD) colsS[w][p] = cb + 1; ++p; }
            if (v.z == 0.f) { if (p < MAXD) colsS[w][p] = cb + 2; ++p; }
            if (v.w == 0.f) { if (p < MAXD) colsS[w][p] = cb + 3; ++p; }
            base += __popcll(m0) + __popcll(m1) + __popcll(m2) + __popcll(m3);
        }
    }
    const int d = base < MAXD ? base : MAXD;
    if (lane == 0) deg[row] = d;
    cols[(size_t)row*MAXD + lane]      = colsS[w][lane];
    cols[(size_t)row*MAXD + 64 + lane] = colsS[w][64 + lane];

    // ---- scores: one float4 gather per edge serves all 4 heads ----
    const float4 f1 = *(const float4*)(f1v4 + (size_t)row*NH);
    const int c0 = colsS[w][lane], c1 = colsS[w][64 + lane];
    float4 s0 = make_float4(-1e30f,-1e30f,-1e30f,-1e30f), s1 = s0;
    if (lane < d) {
        const float4 F = *(const float4*)(f2v4 + (size_t)c0*NH);
        float x;
        x = f1.x + F.x; s0.x = x > 0.f ? x : ALPHA*x;
        x = f1.y + F.y; s0.y = x > 0.f ? x : ALPHA*x;
        x = f1.z + F.z; s0.z = x > 0.f ? x : ALPHA*x;
        x = f1.w + F.w; s0.w = x > 0.f ? x : ALPHA*x;
    }
    if (lane + 64 < d) {
        const float4 F = *(const float4*)(f2v4 + (size_t)c1*NH);
        float x;
        x = f1.x + F.x; s1.x = x > 0.f ? x : ALPHA*x;
        x = f1.y + F.y; s1.y = x > 0.f ? x : ALPHA*x;
        x = f1.z + F.z; s1.z = x > 0.f ? x : ALPHA*x;
        x = f1.w + F.w; s1.w = x > 0.f ? x : ALPHA*x;
    }
    float4 m;
    m.x = fmaxf(s0.x, s1.x); m.y = fmaxf(s0.y, s1.y);
    m.z = fmaxf(s0.z, s1.z); m.w = fmaxf(s0.w, s1.w);
    #pragma unroll
    for (int off = 32; off; off >>= 1) {
        m.x = fmaxf(m.x, __shfl_xor(m.x, off));
        m.y = fmaxf(m.y, __shfl_xor(m.y, off));
        m.z = fmaxf(m.z, __shfl_xor(m.z, off));
        m.w = fmaxf(m.w, __shfl_xor(m.w, off));
    }
    float4 p0 = make_float4(0,0,0,0), p1 = p0;
    if (lane < d) {
        p0.x = expf(s0.x - m.x); p0.y = expf(s0.y - m.y);
        p0.z = expf(s0.z - m.z); p0.w = expf(s0.w - m.w);
    }
    if (lane + 64 < d) {
        p1.x = expf(s1.x - m.x); p1.y = expf(s1.y - m.y);
        p1.z = expf(s1.z - m.z); p1.w = expf(s1.w - m.w);
    }
    coefS[w][lane]      = p0;
    coefS[w][64 + lane] = p1;
    float4 sum;
    sum.x = p0.x + p1.x; sum.y = p0.y + p1.y;
    sum.z = p0.z + p1.z; sum.w = p0.w + p1.w;
    #pragma unroll
    for (int off = 32; off; off >>= 1) {
        sum.x += __shfl_xor(sum.x, off);
        sum.y += __shfl_xor(sum.y, off);
        sum.z += __shfl_xor(sum.z, off);
        sum.w += __shfl_xor(sum.w, off);
    }
    const float4 inv = make_float4(1.f/sum.x, 1.f/sum.y, 1.f/sum.z, 1.f/sum.w);

    // ---- PV: 4 heads at once, lane = hid; 4 gathers/edge from [col][h][hid] ----
    float a0 = 0.f, a1 = 0.f, a2 = 0.f, a3 = 0.f;
    #pragma unroll 4
    for (int e = 0; e < d; ++e) {
        const float4 cf = coefS[w][e];
        const float* fp = fts1 + (size_t)colsS[w][e]*(NH*HID);
        a0 += cf.x * fp[0*HID + lane];
        a1 += cf.y * fp[1*HID + lane];
        a2 += cf.z * fp[2*HID + lane];
        a3 += cf.w * fp[3*HID + lane];
    }
    float v;
    v = a0*inv.x + bias1[0*HID + lane]; h1S[w][0*HID + lane] = v > 0.f ? v : expm1f(v);
    v = a1*inv.y + bias1[1*HID + lane]; h1S[w][1*HID + lane] = v > 0.f ? v : expm1f(v);
    v = a2*inv.z + bias1[2*HID + lane]; h1S[w][2*HID + lane] = v > 0.f ? v : expm1f(v);
    v = a3*inv.w + bias1[3*HID + lane]; h1S[w][3*HID + lane] = v > 0.f ? v : expm1f(v);

    // ---- fts2 = h1 @ W2 (per-wave, shfl-reduced) ----
    const int part = lane >> 4, c = lane & 15;
    float s = 0.f;
    #pragma unroll 8
    for (int q = 0; q < 64; ++q)
        s += h1S[w][part*64 + q] * W2[(part*64 + q)*NC + c];
    s += __shfl_xor(s, 16);
    s += __shfl_xor(s, 32);              // all lanes: fts2[c = lane&15]
    if (lane < NC) fts2[(size_t)row*NC + lane] = s;

    float t1 = (lane < NC) ? s * a2s[lane] : 0.f;
    float t2 = (lane < NC) ? s * a2d[lane] : 0.f;
    #pragma unroll
    for (int off = 8; off; off >>= 1) {
        t1 += __shfl_xor(t1, off);
        t2 += __shfl_xor(t2, off);
    }
    if (lane == 0) { g1[row] = t1 + b2s[0]; g2[row] = t2 + b2d[0]; }
}

// ---------------------------------------------------------------------------
// K3: layer-2 sparse attention, 1 wave/node, 4 nodes/block (proven).
// ---------------------------------------------------------------------------
__global__ __launch_bounds__(256) void k_attn2(
    const float* __restrict__ fts2, const float* __restrict__ g1,
    const float* __restrict__ g2, const float* __restrict__ bias2,
    const int* __restrict__ deg, const int* __restrict__ cols,
    float* __restrict__ out)
{
    __shared__ int   colsS[4][MAXD];
    __shared__ float coefS[4][MAXD];
    const int t = threadIdx.x, w = t >> 6, lane = t & 63;
    const int i = blockIdx.x*4 + w;
    const int d = deg[i];
    for (int e = lane; e < MAXD; e += 64) colsS[w][e] = (e < d) ? cols[(size_t)i*MAXD + e] : 0;

    const float g1i = g1[i];
    float sc0 = -1e30f, sc1 = -1e30f;
    if (lane < d)      { const float x = g1i + g2[colsS[w][lane]];    sc0 = x > 0.f ? x : ALPHA*x; }
    if (lane + 64 < d) { const float x = g1i + g2[colsS[w][lane+64]]; sc1 = x > 0.f ? x : ALPHA*x; }
    float m = fmaxf(sc0, sc1);
    #pragma unroll
    for (int off = 32; off; off >>= 1) m = fmaxf(m, __shfl_xor(m, off));
    const float p0 = (lane      < d) ? expf(sc0 - m) : 0.f;
    const float p1 = (lane + 64 < d) ? expf(sc1 - m) : 0.f;
    coefS[w][lane] = p0; coefS[w][lane + 64] = p1;
    float sum = p0 + p1;
    #pragma unroll
    for (int off = 32; off; off >>= 1) sum += __shfl_xor(sum, off);
    const float inv = 1.f / sum;

    const int eg = lane >> 4, c = lane & 15;
    float acc = 0.f;
    #pragma unroll 2
    for (int e0 = 0; e0 < d; e0 += 4) {
        const int e = e0 + eg;
        if (e < d) acc += coefS[w][e] * fts2[(size_t)colsS[w][e]*NC + c];
    }
    acc += __shfl_xor(acc, 16);
    acc += __shfl_xor(acc, 32);
    if (lane < NC) out[(size_t)i*NC + lane] = acc*inv + bias2[lane];
}

// ---------------------------------------------------------------------------
extern "C" void kernel_launch(void* const* d_in, const int* in_sizes, int n_in,
                              void* d_out, int out_size, void* d_ws, size_t ws_size,
                              hipStream_t stream)
{
    const float* seq   = (const float*)d_in[0];
    const float* bias  = (const float*)d_in[1];
    const float* W1    = (const float*)d_in[2];
    const float* a1s   = (const float*)d_in[3];
    const float* a1d   = (const float*)d_in[4];
    const float* b1s   = (const float*)d_in[5];
    const float* b1d   = (const float*)d_in[6];
    const float* bias1 = (const float*)d_in[7];
    const float* W2    = (const float*)d_in[8];
    const float* a2s   = (const float*)d_in[9];
    const float* a2d   = (const float*)d_in[10];
    const float* b2s   = (const float*)d_in[11];
    const float* b2d   = (const float*)d_in[12];
    const float* bias2 = (const float*)d_in[13];

    char* ws = (char*)d_ws;
    int*   deg  = (int*)ws;    ws += (size_t)NN * 4;
    int*   cols = (int*)ws;    ws += (size_t)NN * MAXD * 4;
    float* fts1 = (float*)ws;  ws += (size_t)NN * NH * HID * 4;
    float* f1v  = (float*)ws;  ws += (size_t)NN * NH * 4;
    float* f2v  = (float*)ws;  ws += (size_t)NN * NH * 4;
    float* fts2 = (float*)ws;  ws += (size_t)NN * NC * 4;
    float* g1   = (float*)ws;  ws += (size_t)NN * 4;
    float* g2   = (float*)ws;  ws += (size_t)NN * 4;

    hipLaunchKernelGGL(k_gemm, dim3(512), dim3(256), 0, stream,
                       seq, W1, a1s, a1d, b1s, b1d, fts1, f1v, f2v);
    hipLaunchKernelGGL(k_scan_attn, dim3(NN/4), dim3(256), 0, stream,
                       bias, fts1, f1v, f2v, bias1, W2, a2s, a2d, b2s, b2d,
                       deg, cols, fts2, g1, g2);
    hipLaunchKernelGGL(k_attn2, dim3(NN/4), dim3(256), 0, stream,
                       fts2, g1, g2, bias2, deg, cols, (float*)d_out);
}

// Round 7
// 113.894 us; speedup vs baseline: 3.8835x; 1.0196x over previous
//
#include <hip/hip_runtime.h>
#include <hip/hip_bf16.h>
#include <math.h>

#define NN    8192
#define FIN   256
#define HID   64
#define NH    4
#define NC    16
#define MAXD  128
#define ALPHA 0.2f
#define KC    32

// Non-temporal float4 load (evict-first): keeps the 256MB bias stream from
// evicting the L2/L3-resident gather tables (fts1/f2v/W2) the attn phase needs.
// __builtin_nontemporal_load needs a native vector type, not HIP_vector_type.
typedef float nfloat4 __attribute__((ext_vector_type(4)));
__device__ __forceinline__ float4 ldnt4(const float4* p) {
    nfloat4 v = __builtin_nontemporal_load((const nfloat4*)p);
    return make_float4(v.x, v.y, v.z, v.w);
}

// ---------------------------------------------------------------------------
// K1: fts1 = x @ W1 per head + f1/f2 scalars (packed [node][head] = float4).
// 512 blocks = 128 row-tiles x 4 heads. xsT transposed so both LDS operand
// reads are b128.
// ---------------------------------------------------------------------------
__global__ __launch_bounds__(256) void k_gemm(
    const float* __restrict__ seq, const float* __restrict__ W1,
    const float* __restrict__ a1s, const float* __restrict__ a1d,
    const float* __restrict__ b1s, const float* __restrict__ b1d,
    float* __restrict__ fts1, float* __restrict__ f1v, float* __restrict__ f2v)
{
    __shared__ union {
        struct { float xsT[KC][68]; float w[KC][68]; } g;
        struct { float r1[64][17];  float r2[64][17]; } gr;
    } S;
    const int t = threadIdx.x, b = blockIdx.x;
    const int head = b & 3, rowbase = (b >> 2) * 64;
    const int tr = t >> 4, tc = t & 15;

    float acc[4][4] = {};
    for (int kc = 0; kc < FIN / KC; ++kc) {
        #pragma unroll
        for (int i = 0; i < 2; ++i) {
            const int lin = t + i*256;
            const int row = lin >> 3, kq = lin & 7;
            const float4 v = *(const float4*)(seq + (size_t)(rowbase + row)*FIN + kc*KC + kq*4);
            S.g.xsT[kq*4+0][row] = v.x;
            S.g.xsT[kq*4+1][row] = v.y;
            S.g.xsT[kq*4+2][row] = v.z;
            S.g.xsT[kq*4+3][row] = v.w;
        }
        #pragma unroll
        for (int i = 0; i < 2; ++i) {
            const int lin = t + i*256;
            const int k = lin >> 4, dq = lin & 15;
            *(float4*)&S.g.w[k][dq*4] =
                *(const float4*)(W1 + ((size_t)head*FIN + kc*KC + k)*HID + dq*4);
        }
        __syncthreads();
        #pragma unroll 8
        for (int k = 0; k < KC; ++k) {
            const float4 aa = *(const float4*)&S.g.xsT[k][tr*4];
            const float4 bb = *(const float4*)&S.g.w[k][tc*4];
            acc[0][0] += aa.x*bb.x; acc[0][1] += aa.x*bb.y; acc[0][2] += aa.x*bb.z; acc[0][3] += aa.x*bb.w;
            acc[1][0] += aa.y*bb.x; acc[1][1] += aa.y*bb.y; acc[1][2] += aa.y*bb.z; acc[1][3] += aa.y*bb.w;
            acc[2][0] += aa.z*bb.x; acc[2][1] += aa.z*bb.y; acc[2][2] += aa.z*bb.z; acc[2][3] += aa.z*bb.w;
            acc[3][0] += aa.w*bb.x; acc[3][1] += aa.w*bb.y; acc[3][2] += aa.w*bb.z; acc[3][3] += aa.w*bb.w;
        }
        __syncthreads();
    }
    float p1[4], p2[4];
    #pragma unroll
    for (int i = 0; i < 4; ++i) {
        const int node = rowbase + tr*4 + i;
        float4 o; o.x = acc[i][0]; o.y = acc[i][1]; o.z = acc[i][2]; o.w = acc[i][3];
        *(float4*)&fts1[((size_t)node*NH + head)*HID + tc*4] = o;
        float s1 = 0.f, s2 = 0.f;
        #pragma unroll
        for (int j = 0; j < 4; ++j) {
            s1 += acc[i][j] * a1s[head*HID + tc*4 + j];
            s2 += acc[i][j] * a1d[head*HID + tc*4 + j];
        }
        p1[i] = s1; p2[i] = s2;
    }
    #pragma unroll
    for (int i = 0; i < 4; ++i) {
        S.gr.r1[tr*4 + i][tc] = p1[i];
        S.gr.r2[tr*4 + i][tc] = p2[i];
    }
    __syncthreads();
    if (t < 64) {
        float s1 = b1s[head], s2 = b1d[head];
        #pragma unroll
        for (int q = 0; q < 16; ++q) { s1 += S.gr.r1[t][q]; s2 += S.gr.r2[t][q]; }
        f1v[(rowbase + t)*NH + head] = s1;   // [node][head] -> float4-packable
        f2v[(rowbase + t)*NH + head] = s2;
    }
}

// ---------------------------------------------------------------------------
// K2: barrier-free fused {scan -> CSR} + {layer-1 attn, all 4 heads in one
// wave} + {elu/concat, fts2 = h1@W2, g1/g2}. ONE WAVE PER ROW, 4 rows/block.
// Bias stream uses NON-TEMPORAL loads so it cannot evict the gather tables.
// ---------------------------------------------------------------------------
__global__ __launch_bounds__(256) void k_scan_attn(
    const float* __restrict__ bias, const float* __restrict__ fts1,
    const float* __restrict__ f1v4, const float* __restrict__ f2v4,
    const float* __restrict__ bias1, const float* __restrict__ W2,
    const float* __restrict__ a2s, const float* __restrict__ a2d,
    const float* __restrict__ b2s, const float* __restrict__ b2d,
    int* __restrict__ deg, int* __restrict__ cols,
    float* __restrict__ fts2, float* __restrict__ g1, float* __restrict__ g2)
{
    __shared__ int    colsS[4][MAXD];
    __shared__ float4 coefS[4][MAXD];
    __shared__ float  h1S[4][NH*HID];

    const int t = threadIdx.x, w = t >> 6, lane = t & 63;
    const int row = blockIdx.x*4 + w;
    const unsigned long long lt = (1ull << lane) - 1ull;

    colsS[w][lane] = 0; colsS[w][64 + lane] = 0;

    // ---- scan: 32KB row, 32 float4/lane in 4 super-iters, chunk-granular
    //      software pipeline; all stream loads are non-temporal ----
    const float4* rp = (const float4*)(bias + (size_t)row * NN);
    float4 vv[8];
    #pragma unroll
    for (int k = 0; k < 8; ++k) vv[k] = ldnt4(rp + k*64 + lane);
    int base = 0;
    #pragma unroll
    for (int s = 0; s < 4; ++s) {
        #pragma unroll
        for (int k = 0; k < 8; ++k) {
            const float4 v = vv[k];
            if (s < 3) vv[k] = ldnt4(rp + ((s+1)*8 + k)*64 + lane);
            const unsigned long long m0 = __ballot(v.x == 0.f);
            const unsigned long long m1 = __ballot(v.y == 0.f);
            const unsigned long long m2 = __ballot(v.z == 0.f);
            const unsigned long long m3 = __ballot(v.w == 0.f);
            const int cb = ((s*8 + k)*64 + lane)*4;
            int p = base + __popcll(m0&lt) + __popcll(m1&lt)
                         + __popcll(m2&lt) + __popcll(m3&lt);
            if (v.x == 0.f) { if (p < MAXD) colsS[w][p] = cb;     ++p; }
            if (v.y == 0.f) { if (p < MAXD) colsS[w][p] = cb + 1; ++p; }
            if (v.z == 0.f) { if (p < MAXD) colsS[w][p] = cb + 2; ++p; }
            if (v.w == 0.f) { if (p < MAXD) colsS[w][p] = cb + 3; ++p; }
            base += __popcll(m0) + __popcll(m1) + __popcll(m2) + __popcll(m3);
        }
    }
    const int d = base < MAXD ? base : MAXD;
    if (lane == 0) deg[row] = d;
    cols[(size_t)row*MAXD + lane]      = colsS[w][lane];
    cols[(size_t)row*MAXD + 64 + lane] = colsS[w][64 + lane];

    // ---- scores: one float4 gather per edge serves all 4 heads ----
    const float4 f1 = *(const float4*)(f1v4 + (size_t)row*NH);
    const int c0 = colsS[w][lane], c1 = colsS[w][64 + lane];
    float4 s0 = make_float4(-1e30f,-1e30f,-1e30f,-1e30f), s1 = s0;
    if (lane < d) {
        const float4 F = *(const float4*)(f2v4 + (size_t)c0*NH);
        float x;
        x = f1.x + F.x; s0.x = x > 0.f ? x : ALPHA*x;
        x = f1.y + F.y; s0.y = x > 0.f ? x : ALPHA*x;
        x = f1.z + F.z; s0.z = x > 0.f ? x : ALPHA*x;
        x = f1.w + F.w; s0.w = x > 0.f ? x : ALPHA*x;
    }
    if (lane + 64 < d) {
        const float4 F = *(const float4*)(f2v4 + (size_t)c1*NH);
        float x;
        x = f1.x + F.x; s1.x = x > 0.f ? x : ALPHA*x;
        x = f1.y + F.y; s1.y = x > 0.f ? x : ALPHA*x;
        x = f1.z + F.z; s1.z = x > 0.f ? x : ALPHA*x;
        x = f1.w + F.w; s1.w = x > 0.f ? x : ALPHA*x;
    }
    float4 m;
    m.x = fmaxf(s0.x, s1.x); m.y = fmaxf(s0.y, s1.y);
    m.z = fmaxf(s0.z, s1.z); m.w = fmaxf(s0.w, s1.w);
    #pragma unroll
    for (int off = 32; off; off >>= 1) {
        m.x = fmaxf(m.x, __shfl_xor(m.x, off));
        m.y = fmaxf(m.y, __shfl_xor(m.y, off));
        m.z = fmaxf(m.z, __shfl_xor(m.z, off));
        m.w = fmaxf(m.w, __shfl_xor(m.w, off));
    }
    float4 p0 = make_float4(0,0,0,0), p1 = p0;
    if (lane < d) {
        p0.x = expf(s0.x - m.x); p0.y = expf(s0.y - m.y);
        p0.z = expf(s0.z - m.z); p0.w = expf(s0.w - m.w);
    }
    if (lane + 64 < d) {
        p1.x = expf(s1.x - m.x); p1.y = expf(s1.y - m.y);
        p1.z = expf(s1.z - m.z); p1.w = expf(s1.w - m.w);
    }
    coefS[w][lane]      = p0;
    coefS[w][64 + lane] = p1;
    float4 sum;
    sum.x = p0.x + p1.x; sum.y = p0.y + p1.y;
    sum.z = p0.z + p1.z; sum.w = p0.w + p1.w;
    #pragma unroll
    for (int off = 32; off; off >>= 1) {
        sum.x += __shfl_xor(sum.x, off);
        sum.y += __shfl_xor(sum.y, off);
        sum.z += __shfl_xor(sum.z, off);
        sum.w += __shfl_xor(sum.w, off);
    }
    const float4 inv = make_float4(1.f/sum.x, 1.f/sum.y, 1.f/sum.z, 1.f/sum.w);

    // ---- PV: 4 heads at once, lane = hid; each edge fetches one contiguous
    //      1KB block [col][4][64] (L2/L3-hot now that the stream is nt) ----
    float a0 = 0.f, a1 = 0.f, a2 = 0.f, a3 = 0.f;
    #pragma unroll 4
    for (int e = 0; e < d; ++e) {
        const float4 cf = coefS[w][e];
        const float* fp = fts1 + (size_t)colsS[w][e]*(NH*HID);
        a0 += cf.x * fp[0*HID + lane];
        a1 += cf.y * fp[1*HID + lane];
        a2 += cf.z * fp[2*HID + lane];
        a3 += cf.w * fp[3*HID + lane];
    }
    float v;
    v = a0*inv.x + bias1[0*HID + lane]; h1S[w][0*HID + lane] = v > 0.f ? v : expm1f(v);
    v = a1*inv.y + bias1[1*HID + lane]; h1S[w][1*HID + lane] = v > 0.f ? v : expm1f(v);
    v = a2*inv.z + bias1[2*HID + lane]; h1S[w][2*HID + lane] = v > 0.f ? v : expm1f(v);
    v = a3*inv.w + bias1[3*HID + lane]; h1S[w][3*HID + lane] = v > 0.f ? v : expm1f(v);

    // ---- fts2 = h1 @ W2 (per-wave, shfl-reduced) ----
    const int part = lane >> 4, c = lane & 15;
    float s = 0.f;
    #pragma unroll 8
    for (int q = 0; q < 64; ++q)
        s += h1S[w][part*64 + q] * W2[(part*64 + q)*NC + c];
    s += __shfl_xor(s, 16);
    s += __shfl_xor(s, 32);              // all lanes: fts2[c = lane&15]
    if (lane < NC) fts2[(size_t)row*NC + lane] = s;

    float t1 = (lane < NC) ? s * a2s[lane] : 0.f;
    float t2 = (lane < NC) ? s * a2d[lane] : 0.f;
    #pragma unroll
    for (int off = 8; off; off >>= 1) {
        t1 += __shfl_xor(t1, off);
        t2 += __shfl_xor(t2, off);
    }
    if (lane == 0) { g1[row] = t1 + b2s[0]; g2[row] = t2 + b2d[0]; }
}

// ---------------------------------------------------------------------------
// K3: layer-2 sparse attention, 1 wave/node, 4 nodes/block.
// ---------------------------------------------------------------------------
__global__ __launch_bounds__(256) void k_attn2(
    const float* __restrict__ fts2, const float* __restrict__ g1,
    const float* __restrict__ g2, const float* __restrict__ bias2,
    const int* __restrict__ deg, const int* __restrict__ cols,
    float* __restrict__ out)
{
    __shared__ int   colsS[4][MAXD];
    __shared__ float coefS[4][MAXD];
    const int t = threadIdx.x, w = t >> 6, lane = t & 63;
    const int i = blockIdx.x*4 + w;
    const int d = deg[i];
    for (int e = lane; e < MAXD; e += 64) colsS[w][e] = (e < d) ? cols[(size_t)i*MAXD + e] : 0;

    const float g1i = g1[i];
    float sc0 = -1e30f, sc1 = -1e30f;
    if (lane < d)      { const float x = g1i + g2[colsS[w][lane]];    sc0 = x > 0.f ? x : ALPHA*x; }
    if (lane + 64 < d) { const float x = g1i + g2[colsS[w][lane+64]]; sc1 = x > 0.f ? x : ALPHA*x; }
    float m = fmaxf(sc0, sc1);
    #pragma unroll
    for (int off = 32; off; off >>= 1) m = fmaxf(m, __shfl_xor(m, off));
    const float p0 = (lane      < d) ? expf(sc0 - m) : 0.f;
    const float p1 = (lane + 64 < d) ? expf(sc1 - m) : 0.f;
    coefS[w][lane] = p0; coefS[w][lane + 64] = p1;
    float sum = p0 + p1;
    #pragma unroll
    for (int off = 32; off; off >>= 1) sum += __shfl_xor(sum, off);
    const float inv = 1.f / sum;

    const int eg = lane >> 4, c = lane & 15;
    float acc = 0.f;
    #pragma unroll 2
    for (int e0 = 0; e0 < d; e0 += 4) {
        const int e = e0 + eg;
        if (e < d) acc += coefS[w][e] * fts2[(size_t)colsS[w][e]*NC + c];
    }
    acc += __shfl_xor(acc, 16);
    acc += __shfl_xor(acc, 32);
    if (lane < NC) out[(size_t)i*NC + lane] = acc*inv + bias2[lane];
}

// ---------------------------------------------------------------------------
extern "C" void kernel_launch(void* const* d_in, const int* in_sizes, int n_in,
                              void* d_out, int out_size, void* d_ws, size_t ws_size,
                              hipStream_t stream)
{
    const float* seq   = (const float*)d_in[0];
    const float* bias  = (const float*)d_in[1];
    const float* W1    = (const float*)d_in[2];
    const float* a1s   = (const float*)d_in[3];
    const float* a1d   = (const float*)d_in[4];
    const float* b1s   = (const float*)d_in[5];
    const float* b1d   = (const float*)d_in[6];
    const float* bias1 = (const float*)d_in[7];
    const float* W2    = (const float*)d_in[8];
    const float* a2s   = (const float*)d_in[9];
    const float* a2d   = (const float*)d_in[10];
    const float* b2s   = (const float*)d_in[11];
    const float* b2d   = (const float*)d_in[12];
    const float* bias2 = (const float*)d_in[13];

    char* ws = (char*)d_ws;
    int*   deg  = (int*)ws;    ws += (size_t)NN * 4;
    int*   cols = (int*)ws;    ws += (size_t)NN * MAXD * 4;
    float* fts1 = (float*)ws;  ws += (size_t)NN * NH * HID * 4;
    float* f1v  = (float*)ws;  ws += (size_t)NN * NH * 4;
    float* f2v  = (float*)ws;  ws += (size_t)NN * NH * 4;
    float* fts2 = (float*)ws;  ws += (size_t)NN * NC * 4;
    float* g1   = (float*)ws;  ws += (size_t)NN * 4;
    float* g2   = (float*)ws;  ws += (size_t)NN * 4;

    hipLaunchKernelGGL(k_gemm, dim3(512), dim3(256), 0, stream,
                       seq, W1, a1s, a1d, b1s, b1d, fts1, f1v, f2v);
    hipLaunchKernelGGL(k_scan_attn, dim3(NN/4), dim3(256), 0, stream,
                       bias, fts1, f1v, f2v, bias1, W2, a2s, a2d, b2s, b2d,
                       deg, cols, fts2, g1, g2);
    hipLaunchKernelGGL(k_attn2, dim3(NN/4), dim3(256), 0, stream,
                       fts2, g1, g2, bias2, deg, cols, (float*)d_out);
}